// Round 14
// baseline (25.725 us; speedup 1.0000x reference)
//
#include <hip/hip_runtime.h>
#include <hip/hip_bf16.h>
#include <math.h>

#define NSAMP 1024
#define F 256
#define E 128
#define SEQ 257
#define NH 4
#define DK 32

// ws float offsets
#define OFF_PMAX   0      // 128
#define OFF_VF     128    // 256
#define OFF_XL     384    // 128
#define OFF_CV     512    // 128
#define OFF_VLAST  640    // 128
#define OFF_SQ     768    // 128
#define OFF_SK     896    // 128
#define OFF_SCK    1024   // 128
#define OFF_A      1408   // 1024 (a[k*4+h], pre-scaled by 1/sqrt32)
#define OFF_UV     2560   // 256*128 -> ends 35328 floats

__device__ inline float wave_sum(float v) {
#pragma unroll
    for (int off = 32; off >= 1; off >>= 1) v += __shfl_xor(v, off, 64);
    return v;
}
__device__ inline float wave_max(float v) {
#pragma unroll
    for (int off = 32; off >= 1; off >>= 1) v = fmaxf(v, __shfl_xor(v, off, 64));
    return v;
}
__device__ inline float gelu_exact(float x) {
    return 0.5f * x * (1.0f + erff(x * 0.7071067811865476f));
}

// ---------------- preA: 389 blocks x 512 (exact R8) ----------------
__global__ __launch_bounds__(512) void preA_kernel(
    const float* __restrict__ A, const float* __restrict__ feat,
    const float* __restrict__ lab, const float* __restrict__ Wq,
    const float* __restrict__ bq, const float* __restrict__ Wk,
    const float* __restrict__ bk, const float* __restrict__ Wv,
    const float* __restrict__ bv, const float* __restrict__ g1,
    const float* __restrict__ beta1, float* __restrict__ ws)
{
    const int bid = blockIdx.x, tid = threadIdx.x;
    const int wvi = tid >> 6, lane = tid & 63;
    __shared__ float red[512];
    __shared__ float su[128];
    __shared__ float sxl[128];
    __shared__ float suk[128];
    __shared__ float sq[128];

    if (bid < 256) {
        const int k = bid;
        if (wvi == 0) {
            float f0 = feat[k * E + lane], f1 = feat[k * E + lane + 64];
            float sum = wave_sum(f0 + f1);
            float mf = sum * (1.f / E);
            float d0 = f0 - mf, d1 = f1 - mf;
            float ssq = wave_sum(d0 * d0 + d1 * d1);
            if (lane == 0) ws[OFF_VF + k] = ssq * (1.f / E);
            su[lane]      = d0 * g1[lane];
            su[lane + 64] = d1 * g1[lane + 64];
        } else if (wvi == 1) {
            float l0 = lab[lane], l1 = lab[lane + 64];
            float sum = wave_sum(l0 + l1);
            float lm = sum * (1.f / E);
            float d0 = l0 - lm, d1 = l1 - lm;
            float ssv = wave_sum(d0 * d0 + d1 * d1);
            float rstd = rsqrtf(ssv * (1.f / E) + 1e-5f);
            sxl[lane]      = d0 * rstd * g1[lane] + beta1[lane];
            sxl[lane + 64] = d1 * rstd * g1[lane + 64] + beta1[lane + 64];
        }
        __syncthreads();
        {
            const int o = tid & 255, half = tid >> 8;
            const int col = o & 127;
            const float* W = (o < 128) ? Wv : Wk;
            const int e0 = half * 64;
            float acc = 0.f;
#pragma unroll 8
            for (int e = e0; e < e0 + 64; ++e) acc += su[e] * W[e * E + col];
            red[tid] = acc;
        }
        __syncthreads();
        if (tid < 256) {
            const int col = tid & 127;
            float v = red[tid] + red[tid + 256];
            if (tid < 128) ws[OFF_UV + k * E + col] = v;
            else           suk[col] = v;
        }
        __syncthreads();
        {
            const int col = tid & 127, q = tid >> 7;
            float acc = 0.f;
#pragma unroll 8
            for (int e = q * 32; e < q * 32 + 32; ++e) acc += sxl[e] * Wq[e * E + col];
            red[tid] = acc;
        }
        __syncthreads();
        if (tid < 128) sq[tid] = red[tid] + red[tid + 128] + red[tid + 256] + red[tid + 384] + bq[tid];
        __syncthreads();
        if (tid < 128) {
            const int h = tid >> 5, i = tid & 31;
            float p = suk[h * DK + i] * sq[h * DK + i];
#pragma unroll
            for (int off = 16; off >= 1; off >>= 1) p += __shfl_xor(p, off, 64);
            if (i == 0) ws[OFF_A + k * 4 + h] = p * 0.17677669529663687f;
        }
    } else if (bid < 384) {
        float m = 0.f;
        for (int i = (bid - 256) * 512 + tid; i < SEQ * SEQ; i += 128 * 512)
            m = fmaxf(m, fabsf(A[i]));
        red[tid] = m;
        __syncthreads();
        for (int s = 256; s >= 1; s >>= 1) {
            if (tid < s) red[tid] = fmaxf(red[tid], red[tid + s]);
            __syncthreads();
        }
        if (tid == 0) ws[OFF_PMAX + (bid - 256)] = red[0];
    } else {
        const int j = bid - 384;
        if (j < 3) {
            float lv = (tid < 128) ? lab[tid] : 0.f;
            red[tid] = lv;
            __syncthreads();
            for (int s = 256; s >= 1; s >>= 1) { if (tid < s) red[tid] += red[tid + s]; __syncthreads(); }
            const float lm = red[0] * (1.f / E);
            __syncthreads();
            const float dd = lv - lm;
            red[tid] = (tid < 128) ? dd * dd : 0.f;
            __syncthreads();
            for (int s = 256; s >= 1; s >>= 1) { if (tid < s) red[tid] += red[tid + s]; __syncthreads(); }
            const float rstd = rsqrtf(red[0] * (1.f / E) + 1e-5f);
            __syncthreads();
            if (tid < 128) {
                float x = dd * rstd * g1[tid] + beta1[tid];
                su[tid] = x;
                if (j == 0) ws[OFF_XL + tid] = x;
            }
        } else {
            if (tid < 128) su[tid] = beta1[tid];
        }
        __syncthreads();
        const float* W    = (j == 0) ? Wq : (j == 2 || j == 4) ? Wv : Wk;
        const float* bias = (j == 0) ? bq : (j == 2 || j == 4) ? bv : bk;
        const int col = tid & 127;
        const int e0 = (tid >> 7) * 32;
        float acc = 0.f;
#pragma unroll 8
        for (int e = e0; e < e0 + 32; ++e) acc += su[e] * W[e * E + col];
        red[tid] = acc;
        __syncthreads();
        if (tid < 128) {
            const int off = (j == 0) ? OFF_SQ : (j == 1) ? OFF_SK : (j == 2) ? OFF_VLAST
                          : (j == 3) ? OFF_SCK : OFF_CV;
            ws[off + tid] = red[tid] + red[tid + 128] + red[tid + 256] + red[tid + 384] + bias[tid];
        }
    }
}

// ---------------- main: 2 samples/block, 512 threads, 512 blocks (2 blocks/CU) ----------------
// No launch_bounds VGPR forcing (R5's failure mode); ~22 KB LDS -> >=2 blocks/CU naturally.
// Block-level parallelism overlaps barrier drains + idle-wave phases across the 2 blocks.
__global__ __launch_bounds__(512) void main_kernel(
    const float* __restrict__ Z, const float* __restrict__ A,
    const float* __restrict__ Wo, const float* __restrict__ bo,
    const float* __restrict__ W1, const float* __restrict__ b1,
    const float* __restrict__ W2, const float* __restrict__ b2,
    const float* __restrict__ g2, const float* __restrict__ beta2,
    const float* __restrict__ alpha_p, const float* __restrict__ ws,
    float* __restrict__ out)
{
    const int tid = threadIdx.x;
    const int wv = tid >> 6, lane = tid & 63;
    const int n0 = blockIdx.x * 2;
    const int g = tid >> 7;      // 0..3 split group
    const int d = tid & 127;

    __shared__ __align__(16) float wm2[4][256][2];   // [h][k][s] 8 KB
    __shared__ __align__(16) float sa[256][4];       // 4 KB
    __shared__ float smask[256];
    __shared__ float sB[4], sScL[4];
    __shared__ __align__(16) float red[1024];        // 4 KB
    __shared__ __align__(16) float att2[128][2];
    __shared__ float oar[2][128];
    __shared__ __align__(16) float h22[128][2];
    __shared__ __align__(16) float gg2[256][2];
    __shared__ float sSumP[2][4], sP256[2][4], sInv[2][4];

    float tk[4];

    // ---- Phase 1a (waves 0-1): Z-LN. wave2 = mask, wave3 = b/scL, waves 4-7 = sa copy ----
    if (wv < 2) {
        const int n = n0 + wv;
        float z[4];
#pragma unroll
        for (int i = 0; i < 4; ++i) z[i] = Z[n * F + lane + 64 * i];
        float sum = wave_sum(z[0] + z[1] + z[2] + z[3]);
        float mean = sum * (1.f / F);
        float ss = 0.f;
#pragma unroll
        for (int i = 0; i < 4; ++i) { float d2 = z[i] - mean; ss += d2 * d2; }
        ss = wave_sum(ss);
        float rstd = rsqrtf(ss * (1.f / F) + 1e-5f);
#pragma unroll
        for (int i = 0; i < 4; ++i) {
            int k = lane + 64 * i;
            float s = (z[i] - mean) * rstd;
            float vf = ws[OFF_VF + k];
            tk[i] = s * rsqrtf(s * s * vf + 1e-5f);
        }
    } else if (wv == 2) {
        float av[4];
#pragma unroll
        for (int q = 0; q < 4; ++q) av[q] = fabsf(A[(lane * 4 + q) * SEQ + (SEQ - 1)]);
        float m = fmaxf(ws[OFF_PMAX + lane], ws[OFF_PMAX + lane + 64]);
        m = wave_max(m);
#pragma unroll
        for (int q = 0; q < 4; ++q) {
            float cmv = (m > 1e-6f) ? av[q] / m : av[q] + 1e-3f;
            smask[lane * 4 + q] = logf(cmv + 1e-9f);
        }
    } else if (wv == 3) {
        const int h = lane >> 4, i2 = lane & 15;
        const int d0 = h * DK + 2 * i2, d1 = d0 + 1;
        float q0 = ws[OFF_SQ + d0], q1 = ws[OFF_SQ + d1];
        float pb = q0 * ws[OFF_SCK + d0] + q1 * ws[OFF_SCK + d1];
        float ps = q0 * ws[OFF_SK + d0] + q1 * ws[OFF_SK + d1];
#pragma unroll
        for (int off = 8; off >= 1; off >>= 1) {
            pb += __shfl_xor(pb, off, 64);
            ps += __shfl_xor(ps, off, 64);
        }
        if (i2 == 0) {
            const float rs = 0.17677669529663687f;
            sB[h] = pb * rs;
            sScL[h] = ps * rs + logf(1.0f + 1e-9f);
        }
    } else {
        const int idx = (wv - 4) * 64 + lane;   // 0..255
        *(float4*)&sa[idx][0] = *(const float4*)(ws + OFF_A + idx * 4);
    }
    __syncthreads();

    // ---- Phase 2 (waves 0-1): scores + softmax ----
    if (wv < 2) {
        float mk[4], areg[4][4];
#pragma unroll
        for (int i = 0; i < 4; ++i) {
            int k = lane + 64 * i;
            mk[i] = smask[k];
            float4 a4 = *(const float4*)&sa[k][0];
            areg[i][0] = a4.x; areg[i][1] = a4.y; areg[i][2] = a4.z; areg[i][3] = a4.w;
        }
#pragma unroll
        for (int h = 0; h < 4; ++h) {
            float bh = sB[h];
            float scL = sScL[h];
            float sc[4];
            float mx = -1e30f;
#pragma unroll
            for (int i = 0; i < 4; ++i) {
                sc[i] = tk[i] * areg[i][h] + bh + mk[i];
                mx = fmaxf(mx, sc[i]);
            }
            if (lane == 0) mx = fmaxf(mx, scL);
            mx = wave_max(mx);
            float local = 0.f;
            float p[4];
#pragma unroll
            for (int i = 0; i < 4; ++i) { p[i] = expf(sc[i] - mx); local += p[i]; }
            float sumP = wave_sum(local);
#pragma unroll
            for (int i = 0; i < 4; ++i) wm2[h][lane + 64 * i][wv] = p[i] * tk[i];
            if (lane == 0) {
                float p256 = expf(scL - mx);
                sSumP[wv][h] = sumP;
                sP256[wv][h] = p256;
                sInv[wv][h] = 1.f / (sumP + p256);
            }
        }
    }
    __syncthreads();

    // ---- Phase 3: attention combine, k split 4 ways (64 iters) ----
    {
        const int h = d >> 5;
        float a0 = 0.f, a1 = 0.f;
        const float* uvp = ws + OFF_UV + (g * 64) * E + d;
#pragma unroll 8
        for (int kk = 0; kk < 64; ++kk) {
            float uv = uvp[kk * E];
            float2 w = *(const float2*)&wm2[h][g * 64 + kk][0];
            a0 += w.x * uv; a1 += w.y * uv;
        }
        float* r = red + g * 256 + d;   // red[g][s][d]
        r[0] = a0; r[128] = a1;
    }
    __syncthreads();
    if (tid < 256) {
        const int s = tid >> 7, dd = tid & 127, hh = dd >> 5;
        float v = 0.f;
#pragma unroll
        for (int gi = 0; gi < 4; ++gi) v += red[gi * 256 + s * 128 + dd];
        float cv = ws[OFF_CV + dd], vl = ws[OFF_VLAST + dd];
        att2[dd][s] = (v + sSumP[s][hh] * cv + sP256[s][hh] * vl) * sInv[s][hh];
    }
    __syncthreads();

    // ---- Phase 4: o = att @ Wo, e split 4 ways (32 iters) ----
    {
        float a0 = 0.f, a1 = 0.f;
        const float* wop = Wo + (g * 32) * E + d;
#pragma unroll 8
        for (int i = 0; i < 32; ++i) {
            float w = wop[i * E];
            float2 av = *(const float2*)&att2[g * 32 + i][0];
            a0 += av.x * w; a1 += av.y * w;
        }
        float* r = red + g * 256 + d;
        r[0] = a0; r[128] = a1;
    }
    __syncthreads();
    if (tid < 256) {
        const int s = tid >> 7, dd = tid & 127;
        float v = 0.f;
#pragma unroll
        for (int gi = 0; gi < 4; ++gi) v += red[gi * 256 + s * 128 + dd];
        oar[s][dd] = v + bo[dd];
    }
    __syncthreads();

    // ---- Phase 5 (waves 0-1): LN(o) with g2,beta2 ----
    if (wv < 2) {
        float x0 = oar[wv][lane], x1 = oar[wv][lane + 64];
        float sum = wave_sum(x0 + x1);
        float mean = sum * (1.f / E);
        float d0 = x0 - mean, d1 = x1 - mean;
        float ss = wave_sum(d0 * d0 + d1 * d1);
        float rstd = rsqrtf(ss * (1.f / E) + 1e-5f);
        h22[lane][wv]      = d0 * rstd * g2[lane] + beta2[lane];
        h22[lane + 64][wv] = d1 * rstd * g2[lane + 64] + beta2[lane + 64];
    }
    __syncthreads();

    // ---- Phase 6: f1 = gelu(h2 @ W1 + b1), d split 2 ways (64 iters) ----
    {
        const int grp = tid >> 8;       // 0..1
        const int j = tid & 255;
        float a0 = 0.f, a1 = 0.f;
        const float* w1p = W1 + (grp * 64) * (2 * E) + j;
#pragma unroll 8
        for (int i = 0; i < 64; ++i) {
            float w = w1p[i * (2 * E)];
            float2 hv = *(const float2*)&h22[grp * 64 + i][0];
            a0 += hv.x * w; a1 += hv.y * w;
        }
        float* r = red + grp * 512 + j;   // red[grp][s][j]
        r[0] = a0; r[256] = a1;
    }
    __syncthreads();
    {
        const int s = tid >> 8, j = tid & 255;
        float v = red[s * 256 + j] + red[512 + s * 256 + j] + b1[j];
        gg2[j][s] = gelu_exact(v);
    }
    __syncthreads();

    // ---- Phase 7: f2 = gg @ W2 + b2; out, j split 4 ways (64 iters) ----
    {
        float a0 = 0.f, a1 = 0.f;
        const float* w2p = W2 + (g * 64) * E + d;
#pragma unroll 8
        for (int i = 0; i < 64; ++i) {
            float w = w2p[i * E];
            float2 gv = *(const float2*)&gg2[g * 64 + i][0];
            a0 += gv.x * w; a1 += gv.y * w;
        }
        float* r = red + g * 256 + d;
        r[0] = a0; r[128] = a1;
    }
    __syncthreads();
    if (tid < 256) {
        const int s = tid >> 7, dd = tid & 127;
        float f2 = b2[dd];
#pragma unroll
        for (int gi = 0; gi < 4; ++gi) f2 += red[gi * 256 + s * 128 + dd];
        float xl = ws[OFF_XL + dd];
        float alpha = alpha_p[0];
        out[(n0 + s) * E + dd] = alpha * (oar[s][dd] + f2) + xl;
    }
}

extern "C" void kernel_launch(void* const* d_in, const int* in_sizes, int n_in,
                              void* d_out, int out_size, void* d_ws, size_t ws_size,
                              hipStream_t stream) {
    const float* Z     = (const float*)d_in[0];
    const float* A     = (const float*)d_in[1];
    const float* feat  = (const float*)d_in[2];
    const float* lab   = (const float*)d_in[3];
    const float* Wq    = (const float*)d_in[4];
    const float* bq    = (const float*)d_in[5];
    const float* Wk    = (const float*)d_in[6];
    const float* bk    = (const float*)d_in[7];
    const float* Wv    = (const float*)d_in[8];
    const float* bv    = (const float*)d_in[9];
    const float* Wo    = (const float*)d_in[10];
    const float* bo    = (const float*)d_in[11];
    const float* W1    = (const float*)d_in[12];
    const float* b1    = (const float*)d_in[13];
    const float* W2    = (const float*)d_in[14];
    const float* b2    = (const float*)d_in[15];
    const float* g1    = (const float*)d_in[16];
    const float* beta1 = (const float*)d_in[17];
    const float* g2    = (const float*)d_in[18];
    const float* beta2 = (const float*)d_in[19];
    const float* alpha = (const float*)d_in[20];
    float* ws = (float*)d_ws;
    float* out = (float*)d_out;

    hipLaunchKernelGGL(preA_kernel, dim3(389), dim3(512), 0, stream,
                       A, feat, lab, Wq, bq, Wk, bk, Wv, bv, g1, beta1, ws);
    hipLaunchKernelGGL(main_kernel, dim3(NSAMP / 2), dim3(512), 0, stream,
                       Z, A, Wo, bo, W1, b1, W2, b2, g2, beta2, alpha, ws, out);
}

// Round 15
// 21.720 us; speedup vs baseline: 1.1844x; 1.1844x over previous
//
#include <hip/hip_runtime.h>
#include <hip/hip_bf16.h>
#include <math.h>

#define NSAMP 1024
#define F 256
#define E 128
#define SEQ 257
#define NH 4
#define DK 32

// ws float offsets
#define OFF_PMAX   0      // 128
#define OFF_VF     128    // 256
#define OFF_XL     384    // 128
#define OFF_CV     512    // 128
#define OFF_VLAST  640    // 128
#define OFF_SQ     768    // 128
#define OFF_SK     896    // 128
#define OFF_SCK    1024   // 128
#define OFF_A      1408   // 1024 (a[k*4+h], pre-scaled by 1/sqrt32)
#define OFF_UV     2560   // 256*128 -> ends 35328 floats

__device__ inline float wave_sum(float v) {
#pragma unroll
    for (int off = 32; off >= 1; off >>= 1) v += __shfl_xor(v, off, 64);
    return v;
}
__device__ inline float wave_max(float v) {
#pragma unroll
    for (int off = 32; off >= 1; off >>= 1) v = fmaxf(v, __shfl_xor(v, off, 64));
    return v;
}
__device__ inline float gelu_exact(float x) {
    return 0.5f * x * (1.0f + erff(x * 0.7071067811865476f));
}

// ---------------- preA: 389 blocks x 512 ----------------
// blocks [0,256)   : feat row k -> VF, UV[k,:], and a[k][h] (UK + redundant SQ in-block)
// blocks [256,384) : partial abs-max of A -> PMAX
// blocks [384,389) : label LN + matvec j (4-way e-split): 0=SQ 1=SK 2=VLAST 3=SCK 4=CV
__global__ __launch_bounds__(512) void preA_kernel(
    const float* __restrict__ A, const float* __restrict__ feat,
    const float* __restrict__ lab, const float* __restrict__ Wq,
    const float* __restrict__ bq, const float* __restrict__ Wk,
    const float* __restrict__ bk, const float* __restrict__ Wv,
    const float* __restrict__ bv, const float* __restrict__ g1,
    const float* __restrict__ beta1, float* __restrict__ ws)
{
    const int bid = blockIdx.x, tid = threadIdx.x;
    const int wvi = tid >> 6, lane = tid & 63;
    __shared__ float red[512];
    __shared__ float su[128];
    __shared__ float sxl[128];
    __shared__ float suk[128];
    __shared__ float sq[128];

    if (bid < 256) {
        const int k = bid;
        // wave 0: feat row stats; wave 1: label LN (both barrier-free)
        if (wvi == 0) {
            float f0 = feat[k * E + lane], f1 = feat[k * E + lane + 64];
            float sum = wave_sum(f0 + f1);
            float mf = sum * (1.f / E);
            float d0 = f0 - mf, d1 = f1 - mf;
            float ssq = wave_sum(d0 * d0 + d1 * d1);
            if (lane == 0) ws[OFF_VF + k] = ssq * (1.f / E);
            su[lane]      = d0 * g1[lane];
            su[lane + 64] = d1 * g1[lane + 64];
        } else if (wvi == 1) {
            float l0 = lab[lane], l1 = lab[lane + 64];
            float sum = wave_sum(l0 + l1);
            float lm = sum * (1.f / E);
            float d0 = l0 - lm, d1 = l1 - lm;
            float ssv = wave_sum(d0 * d0 + d1 * d1);
            float rstd = rsqrtf(ssv * (1.f / E) + 1e-5f);
            sxl[lane]      = d0 * rstd * g1[lane] + beta1[lane];
            sxl[lane + 64] = d1 * rstd * g1[lane + 64] + beta1[lane + 64];
        }
        __syncthreads();
        // M1: UV (cols via Wv) + UK (cols via Wk), 2-way e-split (64-MAC chains)
        {
            const int o = tid & 255, half = tid >> 8;
            const int col = o & 127;
            const float* W = (o < 128) ? Wv : Wk;
            const int e0 = half * 64;
            float acc = 0.f;
#pragma unroll 8
            for (int e = e0; e < e0 + 64; ++e) acc += su[e] * W[e * E + col];
            red[tid] = acc;
        }
        __syncthreads();
        if (tid < 256) {
            const int col = tid & 127;
            float v = red[tid] + red[tid + 256];
            if (tid < 128) ws[OFF_UV + k * E + col] = v;
            else           suk[col] = v;
        }
        __syncthreads();
        // M2: SQ = sxl @ Wq + bq, 4-way e-split (32-MAC chains)
        {
            const int col = tid & 127, q = tid >> 7;
            float acc = 0.f;
#pragma unroll 8
            for (int e = q * 32; e < q * 32 + 32; ++e) acc += sxl[e] * Wq[e * E + col];
            red[tid] = acc;
        }
        __syncthreads();
        if (tid < 128) sq[tid] = red[tid] + red[tid + 128] + red[tid + 256] + red[tid + 384] + bq[tid];
        __syncthreads();
        // M3: a[k][h] = rs * sum_{i<32} UK[k, h*32+i] * SQ[h*32+i]
        if (tid < 128) {
            const int h = tid >> 5, i = tid & 31;
            float p = suk[h * DK + i] * sq[h * DK + i];
#pragma unroll
            for (int off = 16; off >= 1; off >>= 1) p += __shfl_xor(p, off, 64);
            if (i == 0) ws[OFF_A + k * 4 + h] = p * 0.17677669529663687f;
        }
    } else if (bid < 384) {
        float m = 0.f;
        for (int i = (bid - 256) * 512 + tid; i < SEQ * SEQ; i += 128 * 512)
            m = fmaxf(m, fabsf(A[i]));
        red[tid] = m;
        __syncthreads();
        for (int s = 256; s >= 1; s >>= 1) {
            if (tid < s) red[tid] = fmaxf(red[tid], red[tid + s]);
            __syncthreads();
        }
        if (tid == 0) ws[OFF_PMAX + (bid - 256)] = red[0];
    } else {
        const int j = bid - 384;
        if (j < 3) {
            float lv = (tid < 128) ? lab[tid] : 0.f;
            red[tid] = lv;
            __syncthreads();
            for (int s = 256; s >= 1; s >>= 1) { if (tid < s) red[tid] += red[tid + s]; __syncthreads(); }
            const float lm = red[0] * (1.f / E);
            __syncthreads();
            const float dd = lv - lm;
            red[tid] = (tid < 128) ? dd * dd : 0.f;
            __syncthreads();
            for (int s = 256; s >= 1; s >>= 1) { if (tid < s) red[tid] += red[tid + s]; __syncthreads(); }
            const float rstd = rsqrtf(red[0] * (1.f / E) + 1e-5f);
            __syncthreads();
            if (tid < 128) {
                float x = dd * rstd * g1[tid] + beta1[tid];
                su[tid] = x;
                if (j == 0) ws[OFF_XL + tid] = x;
            }
        } else {
            if (tid < 128) su[tid] = beta1[tid];
        }
        __syncthreads();
        const float* W    = (j == 0) ? Wq : (j == 2 || j == 4) ? Wv : Wk;
        const float* bias = (j == 0) ? bq : (j == 2 || j == 4) ? bv : bk;
        const int col = tid & 127;
        const int e0 = (tid >> 7) * 32;   // 4-way split
        float acc = 0.f;
#pragma unroll 8
        for (int e = e0; e < e0 + 32; ++e) acc += su[e] * W[e * E + col];
        red[tid] = acc;
        __syncthreads();
        if (tid < 128) {
            const int off = (j == 0) ? OFF_SQ : (j == 1) ? OFF_SK : (j == 2) ? OFF_VLAST
                          : (j == 3) ? OFF_SCK : OFF_CV;
            ws[off + tid] = red[tid] + red[tid + 128] + red[tid + 256] + red[tid + 384] + bias[tid];
        }
    }
}

// ---------------- main: 4 samples/block, 1024 threads, 256 blocks (R8, best measured) ----------------
__global__ __launch_bounds__(1024) void main_kernel(
    const float* __restrict__ Z, const float* __restrict__ A,
    const float* __restrict__ Wo, const float* __restrict__ bo,
    const float* __restrict__ W1, const float* __restrict__ b1,
    const float* __restrict__ W2, const float* __restrict__ b2,
    const float* __restrict__ g2, const float* __restrict__ beta2,
    const float* __restrict__ alpha_p, const float* __restrict__ ws,
    float* __restrict__ out)
{
    const int tid = threadIdx.x;
    const int wv = tid >> 6, lane = tid & 63;
    const int n0 = blockIdx.x * 4;

    __shared__ __align__(16) float wm4[4][256][4];   // [h][k][s] 16 KB
    __shared__ __align__(16) float sa[256][4];       // 4 KB
    __shared__ float smask[256];
    __shared__ float sB[4], sScL[4];
    __shared__ __align__(16) float red[4096];        // 16 KB
    __shared__ __align__(16) float att4[128][4];
    __shared__ float oar[4][128];
    __shared__ __align__(16) float h24[128][4];
    __shared__ __align__(16) float gg4[256][4];
    __shared__ float sSumP[4][4], sP256[4][4], sInv[4][4];

    float tk[4];

    // ---- Phase 1a (waves 0-3): Z-LN -> tk regs.
    // ---- Phase 1b: wave4 = mask, wave5 = b/scLast, waves 6-7 = sa prefetch ----
    if (wv < 4) {
        const int n = n0 + wv;
        float z[4];
#pragma unroll
        for (int i = 0; i < 4; ++i) z[i] = Z[n * F + lane + 64 * i];
        float sum = wave_sum(z[0] + z[1] + z[2] + z[3]);
        float mean = sum * (1.f / F);
        float ss = 0.f;
#pragma unroll
        for (int i = 0; i < 4; ++i) { float d2 = z[i] - mean; ss += d2 * d2; }
        ss = wave_sum(ss);
        float rstd = rsqrtf(ss * (1.f / F) + 1e-5f);
#pragma unroll
        for (int i = 0; i < 4; ++i) {
            int k = lane + 64 * i;
            float s = (z[i] - mean) * rstd;
            float vf = ws[OFF_VF + k];
            tk[i] = s * rsqrtf(s * s * vf + 1e-5f);
        }
    } else if (wv == 4) {
        // cmax finish + mask for k<256
        float av[4];
#pragma unroll
        for (int q = 0; q < 4; ++q) av[q] = fabsf(A[(lane * 4 + q) * SEQ + (SEQ - 1)]);
        float m = fmaxf(ws[OFF_PMAX + lane], ws[OFF_PMAX + lane + 64]);
        m = wave_max(m);
#pragma unroll
        for (int q = 0; q < 4; ++q) {
            float cmv = (m > 1e-6f) ? av[q] / m : av[q] + 1e-3f;
            smask[lane * 4 + q] = logf(cmv + 1e-9f);
        }
    } else if (wv == 5) {
        // b_h and scLast: 16-lane group per head
        const int h = lane >> 4, i2 = lane & 15;
        const int d0 = h * DK + 2 * i2, d1 = d0 + 1;
        float q0 = ws[OFF_SQ + d0], q1 = ws[OFF_SQ + d1];
        float pb = q0 * ws[OFF_SCK + d0] + q1 * ws[OFF_SCK + d1];
        float ps = q0 * ws[OFF_SK + d0] + q1 * ws[OFF_SK + d1];
#pragma unroll
        for (int off = 8; off >= 1; off >>= 1) {
            pb += __shfl_xor(pb, off, 64);
            ps += __shfl_xor(ps, off, 64);
        }
        if (i2 == 0) {
            const float rs = 0.17677669529663687f;
            sB[h] = pb * rs;
            sScL[h] = ps * rs + logf(1.0f + 1e-9f);
        }
    } else if (wv < 8) {
        const int idx = (wv - 6) * 128 + lane * 2;
        *(float4*)&sa[idx][0]     = *(const float4*)(ws + OFF_A + idx * 4);
        *(float4*)&sa[idx + 1][0] = *(const float4*)(ws + OFF_A + idx * 4 + 4);
    }
    __syncthreads();

    // ---- Phase 2 (waves 0-3): scores + softmax ----
    if (wv < 4) {
        float mk[4], areg[4][4];
#pragma unroll
        for (int i = 0; i < 4; ++i) {
            int k = lane + 64 * i;
            mk[i] = smask[k];
            float4 a4 = *(const float4*)&sa[k][0];
            areg[i][0] = a4.x; areg[i][1] = a4.y; areg[i][2] = a4.z; areg[i][3] = a4.w;
        }
#pragma unroll
        for (int h = 0; h < 4; ++h) {
            float bh = sB[h];
            float scL = sScL[h];
            float sc[4];
            float mx = -1e30f;
#pragma unroll
            for (int i = 0; i < 4; ++i) {
                sc[i] = tk[i] * areg[i][h] + bh + mk[i];
                mx = fmaxf(mx, sc[i]);
            }
            if (lane == 0) mx = fmaxf(mx, scL);
            mx = wave_max(mx);
            float local = 0.f;
            float p[4];
#pragma unroll
            for (int i = 0; i < 4; ++i) { p[i] = expf(sc[i] - mx); local += p[i]; }
            float sumP = wave_sum(local);
#pragma unroll
            for (int i = 0; i < 4; ++i) wm4[h][lane + 64 * i][wv] = p[i] * tk[i];
            if (lane == 0) {
                float p256 = expf(scL - mx);
                sSumP[wv][h] = sumP;
                sP256[wv][h] = p256;
                sInv[wv][h] = 1.f / (sumP + p256);
            }
        }
    }
    __syncthreads();

    const int g = tid >> 7;      // 0..7 split group
    const int d = tid & 127;

    // ---- Phase 3: attention combine, k split 8 ways (32 iters) ----
    {
        const int h = d >> 5;
        float a0 = 0.f, a1 = 0.f, a2 = 0.f, a3 = 0.f;
        const float* uvp = ws + OFF_UV + (g * 32) * E + d;
#pragma unroll 8
        for (int kk = 0; kk < 32; ++kk) {
            float uv = uvp[kk * E];
            float4 w = *(const float4*)&wm4[h][g * 32 + kk][0];
            a0 += w.x * uv; a1 += w.y * uv; a2 += w.z * uv; a3 += w.w * uv;
        }
        float* r = red + g * 512 + d;   // red[g][s][d]
        r[0] = a0; r[128] = a1; r[256] = a2; r[384] = a3;
    }
    __syncthreads();
    if (tid < 512) {
        const int s = tid >> 7, dd = tid & 127, hh = dd >> 5;
        float v = 0.f;
#pragma unroll
        for (int gi = 0; gi < 8; ++gi) v += red[gi * 512 + s * 128 + dd];
        float cv = ws[OFF_CV + dd], vl = ws[OFF_VLAST + dd];
        att4[dd][s] = (v + sSumP[s][hh] * cv + sP256[s][hh] * vl) * sInv[s][hh];
    }
    __syncthreads();

    // ---- Phase 4: o = att @ Wo, e split 8 ways (16 iters) ----
    {
        float a0 = 0.f, a1 = 0.f, a2 = 0.f, a3 = 0.f;
        const float* wop = Wo + (g * 16) * E + d;
#pragma unroll 8
        for (int i = 0; i < 16; ++i) {
            float w = wop[i * E];
            float4 av = *(const float4*)&att4[g * 16 + i][0];
            a0 += av.x * w; a1 += av.y * w; a2 += av.z * w; a3 += av.w * w;
        }
        float* r = red + g * 512 + d;
        r[0] = a0; r[128] = a1; r[256] = a2; r[384] = a3;
    }
    __syncthreads();
    if (tid < 512) {
        const int s = tid >> 7, dd = tid & 127;
        float v = 0.f;
#pragma unroll
        for (int gi = 0; gi < 8; ++gi) v += red[gi * 512 + s * 128 + dd];
        oar[s][dd] = v + bo[dd];
    }
    __syncthreads();

    // ---- Phase 5 (waves 0-3): LN(o) with g2,beta2 ----
    if (wv < 4) {
        float x0 = oar[wv][lane], x1 = oar[wv][lane + 64];
        float sum = wave_sum(x0 + x1);
        float mean = sum * (1.f / E);
        float d0 = x0 - mean, d1 = x1 - mean;
        float ss = wave_sum(d0 * d0 + d1 * d1);
        float rstd = rsqrtf(ss * (1.f / E) + 1e-5f);
        h24[lane][wv]      = d0 * rstd * g2[lane] + beta2[lane];
        h24[lane + 64][wv] = d1 * rstd * g2[lane + 64] + beta2[lane + 64];
    }
    __syncthreads();

    // ---- Phase 6: f1 = gelu(h2 @ W1 + b1), d split 4 ways (32 iters) ----
    {
        const int grp = tid >> 8;       // 0..3
        const int j = tid & 255;
        float a0 = 0.f, a1 = 0.f, a2 = 0.f, a3 = 0.f;
        const float* w1p = W1 + (grp * 32) * (2 * E) + j;
#pragma unroll 8
        for (int i = 0; i < 32; ++i) {
            float w = w1p[i * (2 * E)];
            float4 hv = *(const float4*)&h24[grp * 32 + i][0];
            a0 += hv.x * w; a1 += hv.y * w; a2 += hv.z * w; a3 += hv.w * w;
        }
        float* r = red + grp * 1024 + j;   // red[grp][s][j]
        r[0] = a0; r[256] = a1; r[512] = a2; r[768] = a3;
    }
    __syncthreads();
    {
        const int s = tid >> 8, j = tid & 255;
        float v = red[s * 256 + j] + red[1024 + s * 256 + j]
                + red[2048 + s * 256 + j] + red[3072 + s * 256 + j] + b1[j];
        gg4[j][s] = gelu_exact(v);
    }
    __syncthreads();

    // ---- Phase 7: f2 = gg @ W2 + b2; out, j split 8 ways (32 iters) ----
    {
        float a0 = 0.f, a1 = 0.f, a2 = 0.f, a3 = 0.f;
        const float* w2p = W2 + (g * 32) * E + d;
#pragma unroll 8
        for (int i = 0; i < 32; ++i) {
            float w = w2p[i * E];
            float4 gv = *(const float4*)&gg4[g * 32 + i][0];
            a0 += gv.x * w; a1 += gv.y * w; a2 += gv.z * w; a3 += gv.w * w;
        }
        float* r = red + g * 512 + d;
        r[0] = a0; r[128] = a1; r[256] = a2; r[384] = a3;
    }
    __syncthreads();
    if (tid < 512) {
        const int s = tid >> 7, dd = tid & 127;
        float f2 = b2[dd];
#pragma unroll
        for (int gi = 0; gi < 8; ++gi) f2 += red[gi * 512 + s * 128 + dd];
        float xl = ws[OFF_XL + dd];
        float alpha = alpha_p[0];
        out[(n0 + s) * E + dd] = alpha * (oar[s][dd] + f2) + xl;
    }
}

extern "C" void kernel_launch(void* const* d_in, const int* in_sizes, int n_in,
                              void* d_out, int out_size, void* d_ws, size_t ws_size,
                              hipStream_t stream) {
    const float* Z     = (const float*)d_in[0];
    const float* A     = (const float*)d_in[1];
    const float* feat  = (const float*)d_in[2];
    const float* lab   = (const float*)d_in[3];
    const float* Wq    = (const float*)d_in[4];
    const float* bq    = (const float*)d_in[5];
    const float* Wk    = (const float*)d_in[6];
    const float* bk    = (const float*)d_in[7];
    const float* Wv    = (const float*)d_in[8];
    const float* bv    = (const float*)d_in[9];
    const float* Wo    = (const float*)d_in[10];
    const float* bo    = (const float*)d_in[11];
    const float* W1    = (const float*)d_in[12];
    const float* b1    = (const float*)d_in[13];
    const float* W2    = (const float*)d_in[14];
    const float* b2    = (const float*)d_in[15];
    const float* g1    = (const float*)d_in[16];
    const float* beta1 = (const float*)d_in[17];
    const float* g2    = (const float*)d_in[18];
    const float* beta2 = (const float*)d_in[19];
    const float* alpha = (const float*)d_in[20];
    float* ws = (float*)d_ws;
    float* out = (float*)d_out;

    hipLaunchKernelGGL(preA_kernel, dim3(389), dim3(512), 0, stream,
                       A, feat, lab, Wq, bq, Wk, bk, Wv, bv, g1, beta1, ws);
    hipLaunchKernelGGL(main_kernel, dim3(NSAMP / 4), dim3(1024), 0, stream,
                       Z, A, Wo, bo, W1, b1, W2, b2, g2, beta2, alpha, ws, out);
}